// Round 7
// baseline (1423.577 us; speedup 1.0000x reference)
//
#include <hip/hip_runtime.h>

#define TT 50
#define BB 512
#define II 784
#define HH 800
#define OO 10
#define BH (BB*HH)   // 409600
#define MM (TT*BB)   // 25600

typedef double d4 __attribute__((ext_vector_type(4)));

// Decode a probe-sum value back to a row/col index 0..15.
// Family 1 (holders {u, u+16, u+32, u+48}): V = 4u + 96  (V-96 ≡ 0 mod 4)
// Family 2 (holders {4u .. 4u+3}):          V = 16u + 6  (V-96 ≡ 2 mod 4)
__device__ __forceinline__ int dec16(double V) {
    const int vi = (int)(V + 0.5);
    const int a = vi - 96;
    if (a >= 0 && a < 64 && (a & 3) == 0) return a >> 2;
    return ((vi - 6) >> 4) & 15;
}
__device__ __forceinline__ bool isf1(double V) {
    const int vi = (int)(V + 0.5);
    const int a = vi - 96;
    return (a >= 0 && a < 64 && (a & 3) == 0);
}

// Chunk compute from PRECOMPUTED lane-base pointers: every access is
// base[compile-time-const] -> ds_read_b32 offset:imm, zero address VALU.
// Same values & MFMA chain order as R5 (bit-exact).
__device__ __forceinline__ void g1_comp(
    const float* __restrict__ pA, const float* __restrict__ pB, d4 acc[2][5])
{
    #pragma unroll
    for (int s = 0; s < 4; ++s) {
        const double a0d = (double)pA[s*576];        // (4s+akk)*144 base-folded
        const double a1d = (double)pA[s*576 + 16];
        double bd[5];
        #pragma unroll
        for (int j = 0; j < 5; ++j)
            bd[j] = (double)pB[s*320 + 16*j];
        #pragma unroll
        for (int j = 0; j < 5; ++j) {
            acc[0][j] = __builtin_amdgcn_mfma_f64_16x16x4f64(
                a0d, bd[j], acc[0][j], 0, 0, 0);
            acc[1][j] = __builtin_amdgcn_mfma_f64_16x16x4f64(
                a1d, bd[j], acc[1][j], 0, 0, 0);
        }
    }
}

// ---------------------------------------------------------------------------
// K1: x1d[m][n] = sum_k x[m][k]*W1[n][k] + b1[n], f64 via v_mfma_f64_16x16x4
// (order-safe: any f64 order matches ref's layer-1 exactly — R1/R3 proof).
// M=25600, N=800, K=784. Block tile 128m x 80n, grid 200 x 10, 4 waves.
// R6 POST-MORTEM: MfmaUtil+VALUBusy pegged at ~93% in EVERY config (R2/R3/
// R5/R6) — SIMD issue saturation. KC=8 doubled per-chunk overhead -> VALU 36%.
// The lever is non-MFMA instruction COUNT per MFMA, not barriers/cvt site.
// R7: R5 base (652us proven: f32 LDS, KC=16, dbuf, 1 barrier/chunk, reg
// prefetch) + STATIC ADDRESSING: two named LDS buffers, chunk loop unrolled
// x2 (even->buf0, odd->buf1), read/write lane-base pointers precomputed
// once -> all 28 reads + 12 writes per chunk are base[const] (imm-offset
// ds ops, mergeable to ds_read2), zero per-access VALU.
// Values and MFMA chain order identical to R5 -> bit-exact.
// LAYOUT SELF-CALIBRATION (proven R2): two probe MFMAs recover the true A/B
// lane->(row,k) feed split AND per-register C/D (row,col) positions.
// ---------------------------------------------------------------------------
__global__ __launch_bounds__(256) void k_gemm1(
    const float* __restrict__ x, const float* __restrict__ W1,
    const float* __restrict__ b1, double* __restrict__ x1d)
{
    __shared__ float As0[16*144], As1[16*144];   // [k][m], stride 144
    __shared__ float Bs0[16*80],  Bs1[16*80];    // [k][n], stride 80
    const int m0 = blockIdx.x * 128;
    const int n0 = blockIdx.y * 80;
    const int tid = threadIdx.x;
    const int lane = tid & 63;
    const int wm = (tid >> 6) * 32;    // wave m-offset

    // ---- layout probes (2 MFMAs, negligible) ----
    const d4 zc = {0.0, 0.0, 0.0, 0.0};
    const d4 pr = __builtin_amdgcn_mfma_f64_16x16x4f64(
        (double)lane, 1.0, zc, 0, 0, 0);
    const d4 pc = __builtin_amdgcn_mfma_f64_16x16x4f64(
        1.0, (double)lane, zc, 0, 0, 0);
    int rowIdx[4], colIdx[4];
    #pragma unroll
    for (int r = 0; r < 4; ++r) {
        rowIdx[r] = dec16(pr[r]) & 15;
        colIdx[r] = dec16(pc[r]) & 15;
    }
    const bool af1 = isf1(pr[0]);
    const bool bf1 = isf1(pc[0]);
    const int arow = af1 ? (lane & 15) : (lane >> 2);
    const int akk  = af1 ? (lane >> 4) : (lane & 3);
    const int bcol = bf1 ? (lane & 15) : (lane >> 2);
    const int bkk  = bf1 ? (lane >> 4) : (lane & 3);

    d4 acc[2][5] = {};

    // A staging (R3-proven, 2-way-free): row sm (0..127), k-offset sk (0/8)
    const int sm = tid >> 1;
    const int sk = (tid & 1) * 8;
    // B staging: 80n x 16k = 320 float4 tasks: tid (n 0..63), tid+256 (tid<64)
    const int bn0 = tid >> 2, bk0 = (tid & 3) * 4;
    const int q1  = tid + 256;
    const int bn1 = q1 >> 2,  bk1 = (q1 & 3) * 4;

    // ---- precomputed base pointers (loop-invariant) ----
    const float* pA0r = As0 + akk*144 + wm + arow;   // read bases
    const float* pA1r = As1 + akk*144 + wm + arow;
    const float* pB0r = Bs0 + bkk*80 + bcol;
    const float* pB1r = Bs1 + bkk*80 + bcol;
    float* wA0 = As0 + sk*144 + sm;                  // write bases
    float* wA1 = As1 + sk*144 + sm;
    float* wB0a = Bs0 + bk0*80 + bn0;
    float* wB1a = Bs1 + bk0*80 + bn0;
    float* wB0b = Bs0 + bk1*80 + bn1;
    float* wB1b = Bs1 + bk1*80 + bn1;

    const float* aptr  = x  + (long)(m0+sm)*II + sk;
    const float* bptrA = W1 + (long)(n0+bn0)*II + bk0;
    const float* bptrB = W1 + (long)(n0+bn1)*II + bk1;   // deref only tid<64

#define G1_STORE(WA, WBa, WBb, A0, A1, W0, W1v) do {                     \
        WA[0*144] = A0.x;  WA[1*144] = A0.y;                             \
        WA[2*144] = A0.z;  WA[3*144] = A0.w;                             \
        WA[4*144] = A1.x;  WA[5*144] = A1.y;                             \
        WA[6*144] = A1.z;  WA[7*144] = A1.w;                             \
        WBa[0*80] = W0.x;  WBa[1*80] = W0.y;                             \
        WBa[2*80] = W0.z;  WBa[3*80] = W0.w;                             \
        if (tid < 64) {                                                  \
            WBb[0*80] = W1v.x;  WBb[1*80] = W1v.y;                       \
            WBb[2*80] = W1v.z;  WBb[3*80] = W1v.w;                       \
        }                                                                \
    } while (0)

    float4 a0A, a1A, w0A, w1A;   // prefetch set A (even chunks)
    float4 a0B, a1B, w0B, w1B;   // prefetch set B (odd chunks)

    // prefetch chunk 0 into set A
    a0A = *(const float4*)(aptr);
    a1A = *(const float4*)(aptr + 4);
    w0A = *(const float4*)(bptrA);
    if (tid < 64) w1A = *(const float4*)(bptrB);

    int kofs = 16;
    for (int i = 0; i < 24; ++i) {          // 49 chunks = 24 pairs + tail
        // even chunk 2i: store set A -> buf0, prefetch 2i+1 -> set B
        G1_STORE(wA0, wB0a, wB0b, a0A, a1A, w0A, w1A);
        a0B = *(const float4*)(aptr + kofs);
        a1B = *(const float4*)(aptr + kofs + 4);
        w0B = *(const float4*)(bptrA + kofs);
        if (tid < 64) w1B = *(const float4*)(bptrB + kofs);
        __syncthreads();
        g1_comp(pA0r, pB0r, acc);
        // odd chunk 2i+1: store set B -> buf1, prefetch 2i+2 -> set A
        G1_STORE(wA1, wB1a, wB1b, a0B, a1B, w0B, w1B);
        a0A = *(const float4*)(aptr + kofs + 16);
        a1A = *(const float4*)(aptr + kofs + 20);
        w0A = *(const float4*)(bptrA + kofs + 16);
        if (tid < 64) w1A = *(const float4*)(bptrB + kofs + 16);
        __syncthreads();
        g1_comp(pA1r, pB1r, acc);
        kofs += 32;
    }
    // tail chunk 48 (in set A)
    G1_STORE(wA0, wB0a, wB0b, a0A, a1A, w0A, w1A);
    __syncthreads();
    g1_comp(pA0r, pB0r, acc);

#undef G1_STORE

    #pragma unroll
    for (int i = 0; i < 2; ++i) {
        #pragma unroll
        for (int r = 0; r < 4; ++r) {
            const long m = m0 + wm + 16*i + rowIdx[r];
            #pragma unroll
            for (int j = 0; j < 5; ++j) {
                const int n = n0 + 16*j + colIdx[r];
                x1d[m*HH + n] = acc[i][j][r] + (double)b1[n];
            }
        }
    }
}

// ---------------------------------------------------------------------------
// K2: LIF scan layer 1, f64 (PROVEN path). Reads x1d; writes compact u8
// spikes (ws) + s1r f32 (d_out, write-only).
// ---------------------------------------------------------------------------
__global__ __launch_bounds__(256) void k_mem1(
    const double* __restrict__ x1d, const float* __restrict__ thresh1,
    unsigned char* __restrict__ s1c, float* __restrict__ s1r)
{
    const int lid = blockIdx.x*256 + threadIdx.x;   // = b*HH + h
    const int h = lid % HH;
    const double th = (double)thresh1[h];
    double mem = 0.0;
    for (int t = 0; t < TT; ++t) {
        const long idx = (long)t*BH + lid;
        mem = 0.95*mem + x1d[idx];
        const bool spk = mem > th;
        s1c[idx] = spk ? 1 : 0;
        s1r[idx] = spk ? 1.0f : 0.0f;
        if (spk) mem = 0.0;
    }
}

// ---------------------------------------------------------------------------
// K3: z2[m][n] = chain_k( s1[m][k]*W2[n][k] ) — strict ascending-k single
// __fmaf_rn chain per output (EXACT R5 layer-2 semantics; u8->f32 is exact).
// Tile 128m x 80n, frag 8m(contig) x (4n contig + 1), grid 200x10.
// R5 skeleton (KC=16 dbuf, one barrier/chunk) + R6 vectorized LDS reads
// (helped ~30us). Same values, same fma order -> bit-exact.
// ---------------------------------------------------------------------------
__global__ __launch_bounds__(256) void k_gemm2(
    const unsigned char* __restrict__ s1c, const float* __restrict__ W2,
    float* __restrict__ z2)
{
    __shared__ float As[2][16*132];
    __shared__ float Bs[2][16*84];
    const int m0 = blockIdx.x * 128;
    const int n0 = blockIdx.y * 80;
    const int tid = threadIdx.x;
    const int tx = tid & 15, ty = tid >> 4;
    float acc[8][5] = {};

    // A staging: row am (0..127), k-offset ak (0 or 8), uint2 = 8 u8
    const int am = tid >> 1;
    const int ak = (tid & 1) * 8;
    // B staging: 80n x 16k = 320 float4 tasks: tid (bn 0..63), tid+256 (tid<64)
    const int bn0 = tid >> 2, bk0 = (tid & 3) * 4;
    const int q1 = tid + 256;
    const int bn1 = q1 >> 2, bk1 = (q1 & 3) * 4;

    const unsigned char* ap = s1c + (long)(m0+am)*HH + ak;
    const float* bp0 = W2 + (long)(n0+bn0)*HH + bk0;
    const float* bp1 = W2 + (long)(n0+bn1)*HH + bk1;

    // prefetch chunk 0
    uint2 ra = *(const uint2*)(ap);
    float4 rb0 = *(const float4*)(bp0);
    float4 rb1;
    if (tid < 64) rb1 = *(const float4*)(bp1);

    for (int c = 0; c < 50; ++c) {        // 800 = 50*16
        float* Ad = &As[c & 1][0];
        float* Bd = &Bs[c & 1][0];
        {
            const unsigned int lo = ra.x, hi = ra.y;
            Ad[(ak+0)*132+am] = (float)( lo        & 0xffu);
            Ad[(ak+1)*132+am] = (float)((lo >>  8) & 0xffu);
            Ad[(ak+2)*132+am] = (float)((lo >> 16) & 0xffu);
            Ad[(ak+3)*132+am] = (float)((lo >> 24) & 0xffu);
            Ad[(ak+4)*132+am] = (float)( hi        & 0xffu);
            Ad[(ak+5)*132+am] = (float)((hi >>  8) & 0xffu);
            Ad[(ak+6)*132+am] = (float)((hi >> 16) & 0xffu);
            Ad[(ak+7)*132+am] = (float)((hi >> 24) & 0xffu);
        }
        Bd[(bk0+0)*84+bn0] = rb0.x;
        Bd[(bk0+1)*84+bn0] = rb0.y;
        Bd[(bk0+2)*84+bn0] = rb0.z;
        Bd[(bk0+3)*84+bn0] = rb0.w;
        if (tid < 64) {
            Bd[(bk1+0)*84+bn1] = rb1.x;
            Bd[(bk1+1)*84+bn1] = rb1.y;
            Bd[(bk1+2)*84+bn1] = rb1.z;
            Bd[(bk1+3)*84+bn1] = rb1.w;
        }
        if (c + 1 < 50) {
            const int k0 = (c + 1) * 16;
            ra = *(const uint2*)(ap + k0);
            rb0 = *(const float4*)(bp0 + k0);
            if (tid < 64) rb1 = *(const float4*)(bp1 + k0);
        }
        __syncthreads();                    // ONE barrier per chunk
        #pragma unroll
        for (int k = 0; k < 16; ++k) {
            const float4 a01 = *(const float4*)&Ad[k*132 + ty*8];
            const float4 a23 = *(const float4*)&Ad[k*132 + ty*8 + 4];
            const float4 bv  = *(const float4*)&Bd[k*84 + tx*4];
            const float  b4s = Bd[k*84 + 64 + tx];
            const float a[8] = {a01.x,a01.y,a01.z,a01.w,
                                a23.x,a23.y,a23.z,a23.w};
            const float b[5] = {bv.x,bv.y,bv.z,bv.w,b4s};
            #pragma unroll
            for (int i = 0; i < 8; ++i)
                #pragma unroll
                for (int j = 0; j < 5; ++j)
                    acc[i][j] = __fmaf_rn(a[i], b[j], acc[i][j]);
        }
    }
    #pragma unroll
    for (int i = 0; i < 8; ++i) {
        const long m = m0 + ty*8 + i;
        #pragma unroll
        for (int j = 0; j < 4; ++j)
            z2[m*HH + n0 + tx*4 + j] = acc[i][j];
        z2[m*HH + n0 + 64 + tx] = acc[i][4];
    }
}

// ---------------------------------------------------------------------------
// K4: layer-2 membrane scan, strict fp32 np order ((0.95f*m)+z)+b2 (EXACT
// R5 semantics). mem2 in registers; writes s2r (d_out) + s2c (ws u8).
// ---------------------------------------------------------------------------
__global__ __launch_bounds__(256) void k_scan2(
    const float* __restrict__ z2, const float* __restrict__ b2,
    const float* __restrict__ thresh2, float* __restrict__ s2r,
    unsigned char* __restrict__ s2c)
{
    const int lid = blockIdx.x*256 + threadIdx.x;   // = b*HH + n
    const int n = lid % HH;
    const float b2v = b2[n];
    const float thv = thresh2[n];
    float m = 0.0f;
    for (int t = 0; t < TT; ++t) {
        const long idx = (long)t*BH + lid;
        const float m2 = __fadd_rn(
            __fadd_rn(__fmul_rn(0.95f, m), z2[idx]), b2v);
        const bool spk = m2 > thv;
        s2r[idx] = spk ? 1.0f : 0.0f;
        s2c[idx] = spk ? 1 : 0;
        m = spk ? 0.0f : m2;
    }
}

// ---------------------------------------------------------------------------
// K5: z3[m][o] = chain_k( s2[m][k]*W3[o][k] ) — strict ascending-k single
// chain (EXACT R5 layer-3 matmul semantics). One thread per m row, 10 accs;
// W3 accesses are wave-uniform -> scalar loads.
// ---------------------------------------------------------------------------
__global__ __launch_bounds__(256) void k_gemm3(
    const unsigned char* __restrict__ s2c, const float* __restrict__ W3,
    float* __restrict__ z3)
{
    const long m = blockIdx.x*256 + threadIdx.x;
    const unsigned char* row = s2c + m*HH;
    float acc[10] = {};
    for (int k0 = 0; k0 < HH; k0 += 16) {
        const uint4 v = *(const uint4*)(row + k0);
        const unsigned int d[4] = {v.x, v.y, v.z, v.w};
        #pragma unroll
        for (int w = 0; w < 4; ++w) {
            #pragma unroll
            for (int j = 0; j < 4; ++j) {
                const float sv = (float)((d[w] >> (8*j)) & 0xffu);
                const int k = k0 + w*4 + j;
                #pragma unroll
                for (int o = 0; o < 10; ++o)
                    acc[o] = __fmaf_rn(sv, W3[o*HH + k], acc[o]);
            }
        }
    }
    #pragma unroll
    for (int o = 0; o < 10; ++o)
        z3[m*OO + o] = acc[o];
}

// ---------------------------------------------------------------------------
// K6: layer-3 membrane scan, strict fp32 (EXACT R5 semantics). Writes s3r +
// out0 (d_out, write-only).
// ---------------------------------------------------------------------------
__global__ __launch_bounds__(256) void k_scan3(
    const float* __restrict__ z3, const float* __restrict__ b3,
    float* __restrict__ s3r, float* __restrict__ out0)
{
    const int gid = blockIdx.x*256 + threadIdx.x;   // = b*OO + o
    if (gid >= BB*OO) return;
    const int o = gid % OO;
    const float b3v = b3[o];
    float mem = 0.0f, cnt = 0.0f;
    for (int t = 0; t < TT; ++t) {
        const float m3 = __fadd_rn(
            __fadd_rn(__fmul_rn(0.95f, mem), z3[(long)t*BB*OO + gid]), b3v);
        const bool spk = m3 > 1.0f;
        s3r[(long)t*BB*OO + gid] = spk ? 1.0f : 0.0f;
        if (spk) cnt = __fadd_rn(cnt, 1.0f);
        mem = spk ? 0.0f : m3;
    }
    out0[gid] = cnt;
}

// ---------------------------------------------------------------------------
extern "C" void kernel_launch(void* const* d_in, const int* in_sizes, int n_in,
                              void* d_out, int out_size, void* d_ws, size_t ws_size,
                              hipStream_t stream)
{
    const float* x   = (const float*)d_in[0];
    const float* W1  = (const float*)d_in[1];
    const float* b1  = (const float*)d_in[2];
    const float* W2  = (const float*)d_in[3];
    const float* b2  = (const float*)d_in[4];
    const float* W3  = (const float*)d_in[5];
    const float* b3  = (const float*)d_in[6];
    const float* th1 = (const float*)d_in[7];
    const float* th2 = (const float*)d_in[8];

    float* out0 = (float*)d_out;                    // (B, OUT)   d_out is
    float* s1r  = out0 + BB*OO;                     // (T, B, H)  WRITE-ONLY
    float* s2r  = s1r + (long)TT*BH;                // (T, B, H)
    float* s3r  = s2r + (long)TT*BH;                // (T, B, OUT)

    // ws layout (total 204.8 MB == R5-proven budget):
    //   [0 .. 163.84 MB)   x1d f64  — dead after k_mem1, region reused:
    //        [0 .. 81.92 MB)      z2 f32  (written by k_gemm2 after k_mem1)
    //        [84 MB .. 85.03 MB)  z3 f32
    //   [163.84 .. 184.32 MB) s1c u8
    //   [184.32 .. 204.80 MB) s2c u8
    char* p = (char*)d_ws;
    double* x1d = (double*)p;
    float*  z2  = (float*)p;
    float*  z3  = (float*)(p + 84000000);
    unsigned char* s1c = (unsigned char*)(p + 163840000);
    unsigned char* s2c = s1c + (size_t)TT*BH;
    (void)ws_size;

    k_gemm1<<<dim3(200,10), dim3(256), 0, stream>>>(x, W1, b1, x1d);
    k_mem1 <<<dim3(1600),   dim3(256), 0, stream>>>(x1d, th1, s1c, s1r);
    k_gemm2<<<dim3(200,10), dim3(256), 0, stream>>>(s1c, W2, z2);
    k_scan2<<<dim3(1600),   dim3(256), 0, stream>>>(z2, b2, th2, s2r, s2c);
    k_gemm3<<<dim3(100),    dim3(256), 0, stream>>>(s2c, W3, z3);
    k_scan3<<<dim3(20),     dim3(256), 0, stream>>>(z3, b3, s3r, out0);
}

// Round 8
// 1232.777 us; speedup vs baseline: 1.1548x; 1.1548x over previous
//
#include <hip/hip_runtime.h>

#define TT 50
#define BB 512
#define II 784
#define HH 800
#define OO 10
#define BH (BB*HH)   // 409600
#define MM (TT*BB)   // 25600

typedef double d4 __attribute__((ext_vector_type(4)));

// Decode a probe-sum value back to a row/col index 0..15.
// Family 1 (holders {u, u+16, u+32, u+48}): V = 4u + 96  (V-96 ≡ 0 mod 4)
// Family 2 (holders {4u .. 4u+3}):          V = 16u + 6  (V-96 ≡ 2 mod 4)
__device__ __forceinline__ int dec16(double V) {
    const int vi = (int)(V + 0.5);
    const int a = vi - 96;
    if (a >= 0 && a < 64 && (a & 3) == 0) return a >> 2;
    return ((vi - 6) >> 4) & 15;
}
__device__ __forceinline__ bool isf1(double V) {
    const int vi = (int)(V + 0.5);
    const int a = vi - 96;
    return (a >= 0 && a < 64 && (a & 3) == 0);
}

// Chunk compute from PRECOMPUTED lane-base pointers: every access is
// base[compile-time-const] -> ds_read_b32 offset:imm, zero address VALU.
// Same values & MFMA chain order as R5/R7 (bit-exact).
__device__ __forceinline__ void g1_comp(
    const float* __restrict__ pA, const float* __restrict__ pB, d4 acc[2][5])
{
    #pragma unroll
    for (int s = 0; s < 4; ++s) {
        const double a0d = (double)pA[s*576];        // (4s+akk)*144 base-folded
        const double a1d = (double)pA[s*576 + 16];
        double bd[5];
        #pragma unroll
        for (int j = 0; j < 5; ++j)
            bd[j] = (double)pB[s*320 + 16*j];
        #pragma unroll
        for (int j = 0; j < 5; ++j) {
            acc[0][j] = __builtin_amdgcn_mfma_f64_16x16x4f64(
                a0d, bd[j], acc[0][j], 0, 0, 0);
            acc[1][j] = __builtin_amdgcn_mfma_f64_16x16x4f64(
                a1d, bd[j], acc[1][j], 0, 0, 0);
        }
    }
}

// ---------------------------------------------------------------------------
// K1: x1d[m][n] = sum_k x[m][k]*W1[n][k] + b1[n], f64 via v_mfma_f64_16x16x4
// (order-safe: any f64 order matches ref's layer-1 exactly — R1/R3 proof).
// M=25600, N=800, K=784. Block tile 128m x 80n, grid 200 x 10, 4 waves.
// R7 POST-MORTEM: static addressing DID cut VALUBusy 26->14.6, but the 2nd
// prefetch register set (+16 VGPR -> 132+80acc) pushed allocation past the
// 2-waves/SIMD boundary: occupancy 22->11.7% (1 block/CU) -> latency-bound
// (MfmaUtil+VALU = 74% != 93% saturation) -> net regression.
// R8: R7 static addressing + SINGLE prefetch set (R5's proven 120-VGPR
// pattern: store regs -> reload same regs) + __launch_bounds__(256,2) to
// pin <=256 regs/wave (2 blocks/CU).  Expect issue saturation to return:
// MFMA ~= 93 - 15 ~= 78%.
// Values and MFMA chain order identical to R5/R7 -> bit-exact.
// LAYOUT SELF-CALIBRATION (proven R2): two probe MFMAs recover the true A/B
// lane->(row,k) feed split AND per-register C/D (row,col) positions.
// ---------------------------------------------------------------------------
__global__ __launch_bounds__(256, 2) void k_gemm1(
    const float* __restrict__ x, const float* __restrict__ W1,
    const float* __restrict__ b1, double* __restrict__ x1d)
{
    __shared__ float As0[16*144], As1[16*144];   // [k][m], stride 144
    __shared__ float Bs0[16*80],  Bs1[16*80];    // [k][n], stride 80
    const int m0 = blockIdx.x * 128;
    const int n0 = blockIdx.y * 80;
    const int tid = threadIdx.x;
    const int lane = tid & 63;
    const int wm = (tid >> 6) * 32;    // wave m-offset

    // ---- layout probes (2 MFMAs, negligible) ----
    const d4 zc = {0.0, 0.0, 0.0, 0.0};
    const d4 pr = __builtin_amdgcn_mfma_f64_16x16x4f64(
        (double)lane, 1.0, zc, 0, 0, 0);
    const d4 pc = __builtin_amdgcn_mfma_f64_16x16x4f64(
        1.0, (double)lane, zc, 0, 0, 0);
    int rowIdx[4], colIdx[4];
    #pragma unroll
    for (int r = 0; r < 4; ++r) {
        rowIdx[r] = dec16(pr[r]) & 15;
        colIdx[r] = dec16(pc[r]) & 15;
    }
    const bool af1 = isf1(pr[0]);
    const bool bf1 = isf1(pc[0]);
    const int arow = af1 ? (lane & 15) : (lane >> 2);
    const int akk  = af1 ? (lane >> 4) : (lane & 3);
    const int bcol = bf1 ? (lane & 15) : (lane >> 2);
    const int bkk  = bf1 ? (lane >> 4) : (lane & 3);

    d4 acc[2][5] = {};

    // A staging (R3-proven, 2-way-free): row sm (0..127), k-offset sk (0/8)
    const int sm = tid >> 1;
    const int sk = (tid & 1) * 8;
    // B staging: 80n x 16k = 320 float4 tasks: tid (n 0..63), tid+256 (tid<64)
    const int bn0 = tid >> 2, bk0 = (tid & 3) * 4;
    const int q1  = tid + 256;
    const int bn1 = q1 >> 2,  bk1 = (q1 & 3) * 4;

    // ---- precomputed base pointers (loop-invariant) ----
    const float* pA0r = As0 + akk*144 + wm + arow;   // read bases
    const float* pA1r = As1 + akk*144 + wm + arow;
    const float* pB0r = Bs0 + bkk*80 + bcol;
    const float* pB1r = Bs1 + bkk*80 + bcol;
    float* wA0 = As0 + sk*144 + sm;                  // write bases
    float* wA1 = As1 + sk*144 + sm;
    float* wB0a = Bs0 + bk0*80 + bn0;
    float* wB1a = Bs1 + bk0*80 + bn0;
    float* wB0b = Bs0 + bk1*80 + bn1;
    float* wB1b = Bs1 + bk1*80 + bn1;

    const float* aptr  = x  + (long)(m0+sm)*II + sk;
    const float* bptrA = W1 + (long)(n0+bn0)*II + bk0;
    const float* bptrB = W1 + (long)(n0+bn1)*II + bk1;   // deref only tid<64

#define G1_STORE(WA, WBa, WBb) do {                                      \
        WA[0*144] = a0.x;  WA[1*144] = a0.y;                             \
        WA[2*144] = a0.z;  WA[3*144] = a0.w;                             \
        WA[4*144] = a1.x;  WA[5*144] = a1.y;                             \
        WA[6*144] = a1.z;  WA[7*144] = a1.w;                             \
        WBa[0*80] = w0.x;  WBa[1*80] = w0.y;                             \
        WBa[2*80] = w0.z;  WBa[3*80] = w0.w;                             \
        if (tid < 64) {                                                  \
            WBb[0*80] = w1.x;  WBb[1*80] = w1.y;                         \
            WBb[2*80] = w1.z;  WBb[3*80] = w1.w;                         \
        }                                                                \
    } while (0)

#define G1_LOAD(OFS) do {                                                \
        a0 = *(const float4*)(aptr + (OFS));                             \
        a1 = *(const float4*)(aptr + (OFS) + 4);                         \
        w0 = *(const float4*)(bptrA + (OFS));                            \
        if (tid < 64) w1 = *(const float4*)(bptrB + (OFS));              \
    } while (0)

    float4 a0, a1, w0, w1;   // SINGLE prefetch set (R5-proven reg budget)

    G1_LOAD(0);              // prefetch chunk 0

    int kofs = 16;
    for (int i = 0; i < 24; ++i) {          // 49 chunks = 24 pairs + tail
        // even chunk 2i: store -> buf0, prefetch 2i+1
        G1_STORE(wA0, wB0a, wB0b);
        G1_LOAD(kofs);
        __syncthreads();
        g1_comp(pA0r, pB0r, acc);
        // odd chunk 2i+1: store -> buf1, prefetch 2i+2
        G1_STORE(wA1, wB1a, wB1b);
        G1_LOAD(kofs + 16);
        __syncthreads();
        g1_comp(pA1r, pB1r, acc);
        kofs += 32;
    }
    // tail chunk 48 (already in regs)
    G1_STORE(wA0, wB0a, wB0b);
    __syncthreads();
    g1_comp(pA0r, pB0r, acc);

#undef G1_STORE
#undef G1_LOAD

    #pragma unroll
    for (int i = 0; i < 2; ++i) {
        #pragma unroll
        for (int r = 0; r < 4; ++r) {
            const long m = m0 + wm + 16*i + rowIdx[r];
            #pragma unroll
            for (int j = 0; j < 5; ++j) {
                const int n = n0 + 16*j + colIdx[r];
                x1d[m*HH + n] = acc[i][j][r] + (double)b1[n];
            }
        }
    }
}

// ---------------------------------------------------------------------------
// K2: LIF scan layer 1, f64 (PROVEN path). Reads x1d; writes compact u8
// spikes (ws) + s1r f32 (d_out, write-only).
// ---------------------------------------------------------------------------
__global__ __launch_bounds__(256) void k_mem1(
    const double* __restrict__ x1d, const float* __restrict__ thresh1,
    unsigned char* __restrict__ s1c, float* __restrict__ s1r)
{
    const int lid = blockIdx.x*256 + threadIdx.x;   // = b*HH + h
    const int h = lid % HH;
    const double th = (double)thresh1[h];
    double mem = 0.0;
    for (int t = 0; t < TT; ++t) {
        const long idx = (long)t*BH + lid;
        mem = 0.95*mem + x1d[idx];
        const bool spk = mem > th;
        s1c[idx] = spk ? 1 : 0;
        s1r[idx] = spk ? 1.0f : 0.0f;
        if (spk) mem = 0.0;
    }
}

// ---------------------------------------------------------------------------
// K3: z2[m][n] = chain_k( s1[m][k]*W2[n][k] ) — strict ascending-k single
// __fmaf_rn chain per output (EXACT R5 layer-2 semantics; u8->f32 is exact).
// Tile 128m x 80n, frag 8m(contig) x (4n contig + 1), grid 200x10.
// R5 skeleton (KC=16 dbuf, one barrier/chunk) + R6 vectorized LDS reads
// (helped ~30us). Same values, same fma order -> bit-exact.
// ---------------------------------------------------------------------------
__global__ __launch_bounds__(256) void k_gemm2(
    const unsigned char* __restrict__ s1c, const float* __restrict__ W2,
    float* __restrict__ z2)
{
    __shared__ float As[2][16*132];
    __shared__ float Bs[2][16*84];
    const int m0 = blockIdx.x * 128;
    const int n0 = blockIdx.y * 80;
    const int tid = threadIdx.x;
    const int tx = tid & 15, ty = tid >> 4;
    float acc[8][5] = {};

    // A staging: row am (0..127), k-offset ak (0 or 8), uint2 = 8 u8
    const int am = tid >> 1;
    const int ak = (tid & 1) * 8;
    // B staging: 80n x 16k = 320 float4 tasks: tid (bn 0..63), tid+256 (tid<64)
    const int bn0 = tid >> 2, bk0 = (tid & 3) * 4;
    const int q1 = tid + 256;
    const int bn1 = q1 >> 2, bk1 = (q1 & 3) * 4;

    const unsigned char* ap = s1c + (long)(m0+am)*HH + ak;
    const float* bp0 = W2 + (long)(n0+bn0)*HH + bk0;
    const float* bp1 = W2 + (long)(n0+bn1)*HH + bk1;

    // prefetch chunk 0
    uint2 ra = *(const uint2*)(ap);
    float4 rb0 = *(const float4*)(bp0);
    float4 rb1;
    if (tid < 64) rb1 = *(const float4*)(bp1);

    for (int c = 0; c < 50; ++c) {        // 800 = 50*16
        float* Ad = &As[c & 1][0];
        float* Bd = &Bs[c & 1][0];
        {
            const unsigned int lo = ra.x, hi = ra.y;
            Ad[(ak+0)*132+am] = (float)( lo        & 0xffu);
            Ad[(ak+1)*132+am] = (float)((lo >>  8) & 0xffu);
            Ad[(ak+2)*132+am] = (float)((lo >> 16) & 0xffu);
            Ad[(ak+3)*132+am] = (float)((lo >> 24) & 0xffu);
            Ad[(ak+4)*132+am] = (float)( hi        & 0xffu);
            Ad[(ak+5)*132+am] = (float)((hi >>  8) & 0xffu);
            Ad[(ak+6)*132+am] = (float)((hi >> 16) & 0xffu);
            Ad[(ak+7)*132+am] = (float)((hi >> 24) & 0xffu);
        }
        Bd[(bk0+0)*84+bn0] = rb0.x;
        Bd[(bk0+1)*84+bn0] = rb0.y;
        Bd[(bk0+2)*84+bn0] = rb0.z;
        Bd[(bk0+3)*84+bn0] = rb0.w;
        if (tid < 64) {
            Bd[(bk1+0)*84+bn1] = rb1.x;
            Bd[(bk1+1)*84+bn1] = rb1.y;
            Bd[(bk1+2)*84+bn1] = rb1.z;
            Bd[(bk1+3)*84+bn1] = rb1.w;
        }
        if (c + 1 < 50) {
            const int k0 = (c + 1) * 16;
            ra = *(const uint2*)(ap + k0);
            rb0 = *(const float4*)(bp0 + k0);
            if (tid < 64) rb1 = *(const float4*)(bp1 + k0);
        }
        __syncthreads();                    // ONE barrier per chunk
        #pragma unroll
        for (int k = 0; k < 16; ++k) {
            const float4 a01 = *(const float4*)&Ad[k*132 + ty*8];
            const float4 a23 = *(const float4*)&Ad[k*132 + ty*8 + 4];
            const float4 bv  = *(const float4*)&Bd[k*84 + tx*4];
            const float  b4s = Bd[k*84 + 64 + tx];
            const float a[8] = {a01.x,a01.y,a01.z,a01.w,
                                a23.x,a23.y,a23.z,a23.w};
            const float b[5] = {bv.x,bv.y,bv.z,bv.w,b4s};
            #pragma unroll
            for (int i = 0; i < 8; ++i)
                #pragma unroll
                for (int j = 0; j < 5; ++j)
                    acc[i][j] = __fmaf_rn(a[i], b[j], acc[i][j]);
        }
    }
    #pragma unroll
    for (int i = 0; i < 8; ++i) {
        const long m = m0 + ty*8 + i;
        #pragma unroll
        for (int j = 0; j < 4; ++j)
            z2[m*HH + n0 + tx*4 + j] = acc[i][j];
        z2[m*HH + n0 + 64 + tx] = acc[i][4];
    }
}

// ---------------------------------------------------------------------------
// K4: layer-2 membrane scan, strict fp32 np order ((0.95f*m)+z)+b2 (EXACT
// R5 semantics). mem2 in registers; writes s2r (d_out) + s2c (ws u8).
// ---------------------------------------------------------------------------
__global__ __launch_bounds__(256) void k_scan2(
    const float* __restrict__ z2, const float* __restrict__ b2,
    const float* __restrict__ thresh2, float* __restrict__ s2r,
    unsigned char* __restrict__ s2c)
{
    const int lid = blockIdx.x*256 + threadIdx.x;   // = b*HH + n
    const int n = lid % HH;
    const float b2v = b2[n];
    const float thv = thresh2[n];
    float m = 0.0f;
    for (int t = 0; t < TT; ++t) {
        const long idx = (long)t*BH + lid;
        const float m2 = __fadd_rn(
            __fadd_rn(__fmul_rn(0.95f, m), z2[idx]), b2v);
        const bool spk = m2 > thv;
        s2r[idx] = spk ? 1.0f : 0.0f;
        s2c[idx] = spk ? 1 : 0;
        m = spk ? 0.0f : m2;
    }
}

// ---------------------------------------------------------------------------
// K5: z3[m][o] = chain_k( s2[m][k]*W3[o][k] ) — strict ascending-k single
// chain (EXACT R5 layer-3 matmul semantics). One thread per m row, 10 accs;
// W3 accesses are wave-uniform -> scalar loads.
// ---------------------------------------------------------------------------
__global__ __launch_bounds__(256) void k_gemm3(
    const unsigned char* __restrict__ s2c, const float* __restrict__ W3,
    float* __restrict__ z3)
{
    const long m = blockIdx.x*256 + threadIdx.x;
    const unsigned char* row = s2c + m*HH;
    float acc[10] = {};
    for (int k0 = 0; k0 < HH; k0 += 16) {
        const uint4 v = *(const uint4*)(row + k0);
        const unsigned int d[4] = {v.x, v.y, v.z, v.w};
        #pragma unroll
        for (int w = 0; w < 4; ++w) {
            #pragma unroll
            for (int j = 0; j < 4; ++j) {
                const float sv = (float)((d[w] >> (8*j)) & 0xffu);
                const int k = k0 + w*4 + j;
                #pragma unroll
                for (int o = 0; o < 10; ++o)
                    acc[o] = __fmaf_rn(sv, W3[o*HH + k], acc[o]);
            }
        }
    }
    #pragma unroll
    for (int o = 0; o < 10; ++o)
        z3[m*OO + o] = acc[o];
}

// ---------------------------------------------------------------------------
// K6: layer-3 membrane scan, strict fp32 (EXACT R5 semantics). Writes s3r +
// out0 (d_out, write-only).
// ---------------------------------------------------------------------------
__global__ __launch_bounds__(256) void k_scan3(
    const float* __restrict__ z3, const float* __restrict__ b3,
    float* __restrict__ s3r, float* __restrict__ out0)
{
    const int gid = blockIdx.x*256 + threadIdx.x;   // = b*OO + o
    if (gid >= BB*OO) return;
    const int o = gid % OO;
    const float b3v = b3[o];
    float mem = 0.0f, cnt = 0.0f;
    for (int t = 0; t < TT; ++t) {
        const float m3 = __fadd_rn(
            __fadd_rn(__fmul_rn(0.95f, mem), z3[(long)t*BB*OO + gid]), b3v);
        const bool spk = m3 > 1.0f;
        s3r[(long)t*BB*OO + gid] = spk ? 1.0f : 0.0f;
        if (spk) cnt = __fadd_rn(cnt, 1.0f);
        mem = spk ? 0.0f : m3;
    }
    out0[gid] = cnt;
}

// ---------------------------------------------------------------------------
extern "C" void kernel_launch(void* const* d_in, const int* in_sizes, int n_in,
                              void* d_out, int out_size, void* d_ws, size_t ws_size,
                              hipStream_t stream)
{
    const float* x   = (const float*)d_in[0];
    const float* W1  = (const float*)d_in[1];
    const float* b1  = (const float*)d_in[2];
    const float* W2  = (const float*)d_in[3];
    const float* b2  = (const float*)d_in[4];
    const float* W3  = (const float*)d_in[5];
    const float* b3  = (const float*)d_in[6];
    const float* th1 = (const float*)d_in[7];
    const float* th2 = (const float*)d_in[8];

    float* out0 = (float*)d_out;                    // (B, OUT)   d_out is
    float* s1r  = out0 + BB*OO;                     // (T, B, H)  WRITE-ONLY
    float* s2r  = s1r + (long)TT*BH;                // (T, B, H)
    float* s3r  = s2r + (long)TT*BH;                // (T, B, OUT)

    // ws layout (total 204.8 MB == R5-proven budget):
    //   [0 .. 163.84 MB)   x1d f64  — dead after k_mem1, region reused:
    //        [0 .. 81.92 MB)      z2 f32  (written by k_gemm2 after k_mem1)
    //        [84 MB .. 85.03 MB)  z3 f32
    //   [163.84 .. 184.32 MB) s1c u8
    //   [184.32 .. 204.80 MB) s2c u8
    char* p = (char*)d_ws;
    double* x1d = (double*)p;
    float*  z2  = (float*)p;
    float*  z3  = (float*)(p + 84000000);
    unsigned char* s1c = (unsigned char*)(p + 163840000);
    unsigned char* s2c = s1c + (size_t)TT*BH;
    (void)ws_size;

    k_gemm1<<<dim3(200,10), dim3(256), 0, stream>>>(x, W1, b1, x1d);
    k_mem1 <<<dim3(1600),   dim3(256), 0, stream>>>(x1d, th1, s1c, s1r);
    k_gemm2<<<dim3(200,10), dim3(256), 0, stream>>>(s1c, W2, z2);
    k_scan2<<<dim3(1600),   dim3(256), 0, stream>>>(z2, b2, th2, s2r, s2c);
    k_gemm3<<<dim3(100),    dim3(256), 0, stream>>>(s2c, W3, z3);
    k_scan3<<<dim3(20),     dim3(256), 0, stream>>>(z3, b3, s3r, out0);
}